// Round 2
// baseline (350.980 us; speedup 1.0000x reference)
//
#include <hip/hip_runtime.h>

#define S_LEN 2048
#define DM 768
#define NH 12
#define DH 64
#define BATCH 2

typedef __attribute__((ext_vector_type(8))) short bf16x8;
typedef __attribute__((ext_vector_type(4))) float f32x4;
typedef __attribute__((ext_vector_type(4))) unsigned short u16x4;

__device__ __forceinline__ unsigned short f2bf(float f) {
  union { float f; unsigned u; } v; v.f = f;
  unsigned r = (v.u + 0x7fffu + ((v.u >> 16) & 1u)) >> 16;
  return (unsigned short)r;
}

// ---------------- Fused Q/K/V projection GEMM ----------------
// C = X @ W + b. Q scaled by 1/8. Q,K stored [b*s][768] bf16.
// V stored TRANSPOSED: Vt[(h*64+d)*BATCH + b][s] bf16, so the attention
// kernel can load PV B-fragments (V^T rows) directly from global.
#define BM 128
#define BN 128
#define BK 32
#define LDPAD 40

__global__ __launch_bounds__(256) void qkv_gemm(
    const float* __restrict__ X,
    const float* __restrict__ Wq, const float* __restrict__ bq,
    const float* __restrict__ Wk, const float* __restrict__ bk,
    const float* __restrict__ Wv, const float* __restrict__ bv,
    unsigned short* __restrict__ Qo, unsigned short* __restrict__ Ko,
    unsigned short* __restrict__ Vo)
{
  const int z = blockIdx.z;
  const float* W    = (z == 0) ? Wq : (z == 1) ? Wk : Wv;
  const float* bias = (z == 0) ? bq : (z == 1) ? bk : bv;
  const float scale = (z == 0) ? 0.125f : 1.0f;

  __shared__ __align__(16) unsigned short Al[BM][LDPAD];
  __shared__ __align__(16) unsigned short Bl[BN][LDPAD];

  const int t = threadIdx.x;
  const int wv = t >> 6, lane = t & 63;
  const int g = lane >> 4, c = lane & 15;
  const int wm = (wv >> 1) * 64, wn = (wv & 1) * 64;
  const int m0 = blockIdx.y * BM, n0 = blockIdx.x * BN;

  f32x4 acc[4][4];
  #pragma unroll
  for (int i = 0; i < 4; ++i)
    #pragma unroll
    for (int j = 0; j < 4; ++j) {
      float bb = bias[n0 + wn + j * 16 + c];
      f32x4 a4 = {bb, bb, bb, bb};
      acc[i][j] = a4;
    }

  const int a_m = t >> 1, a_k = (t & 1) * 16;
  const int b_k = t >> 3, b_n = (t & 7) * 16;

  for (int kt = 0; kt < DM / BK; ++kt) {
    const int k0 = kt * BK;
    __syncthreads();
    {
      const float* src = X + (size_t)(m0 + a_m) * DM + k0 + a_k;
      bf16x8 t0, t1;
      #pragma unroll
      for (int j = 0; j < 8; ++j) { t0[j] = (short)f2bf(src[j]); t1[j] = (short)f2bf(src[8 + j]); }
      *(bf16x8*)&Al[a_m][a_k] = t0;
      *(bf16x8*)&Al[a_m][a_k + 8] = t1;
    }
    {
      const float* src = W + (size_t)(k0 + b_k) * DM + n0 + b_n;
      #pragma unroll
      for (int j = 0; j < 16; ++j) Bl[b_n + j][b_k] = f2bf(src[j]);
    }
    __syncthreads();
    bf16x8 af[4], bfr[4];
    #pragma unroll
    for (int i = 0; i < 4; ++i) af[i]  = *(const bf16x8*)&Al[wm + i * 16 + c][8 * g];
    #pragma unroll
    for (int j = 0; j < 4; ++j) bfr[j] = *(const bf16x8*)&Bl[wn + j * 16 + c][8 * g];
    #pragma unroll
    for (int i = 0; i < 4; ++i)
      #pragma unroll
      for (int j = 0; j < 4; ++j)
        acc[i][j] = __builtin_amdgcn_mfma_f32_16x16x32_bf16(af[i], bfr[j], acc[i][j], 0, 0, 0);
  }

  if (z == 2) {
    // transposed store: Vt[(h*64+d)*BATCH + b][s], pack 4 consecutive s (r=0..3)
    #pragma unroll
    for (int i = 0; i < 4; ++i)
      #pragma unroll
      for (int j = 0; j < 4; ++j) {
        const int n = n0 + wn + j * 16 + c;
        const int hh = n >> 6, d = n & 63;
        const int mm = m0 + wm + i * 16 + 4 * g;
        const int bb = mm >> 11, ss = mm & 2047;
        u16x4 pk;
        #pragma unroll
        for (int r = 0; r < 4; ++r) pk[r] = f2bf(acc[i][j][r]);
        *(u16x4*)&Vo[((size_t)((hh * DH + d) * BATCH + bb)) * S_LEN + ss] = pk;
      }
  } else {
    unsigned short* Out = (z == 0) ? Qo : Ko;
    #pragma unroll
    for (int i = 0; i < 4; ++i)
      #pragma unroll
      for (int j = 0; j < 4; ++j)
        #pragma unroll
        for (int r = 0; r < 4; ++r) {
          const int m = m0 + wm + i * 16 + 4 * g + r;
          const int n = n0 + wn + j * 16 + c;
          Out[(size_t)m * DM + n] = f2bf(acc[i][j][r] * scale);
        }
  }
}

// ---------------- Fused attention (swapped-operand, barrier-free) ----------------
// One block per (b, h, 64 q-rows); 4 independent waves, 16 q-rows each.
// QK^T computed as mfma(K, Q) so each lane holds 4 CONSECUTIVE k-columns of
// ONE q-row (q = lane&15): row softmax is in-thread + 2 shuffles, P store is
// a single dwordx4 per sub-tile, m/l are scalars. V read directly from the
// pre-transposed Vt global buffer -> no V staging, no __syncthreads at all.
__global__ __launch_bounds__(256) void attn_fused(
    const unsigned short* __restrict__ Qb,
    const unsigned short* __restrict__ Kb,
    const unsigned short* __restrict__ Vt,
    const float* __restrict__ mask,   // [B][S]
    float* __restrict__ ctx,          // [B][S][768]
    float* __restrict__ Pout)         // [B][H][S][S]
{
  // bijective XCD swizzle: 768 blocks, 96 per XCD, (b,h) contiguous per XCD
  const int bid = blockIdx.x;
  const int wg = (bid & 7) * 96 + (bid >> 3);
  const int qt = wg & 31;
  const int hb = wg >> 5;
  const int h = hb % NH, b = hb / NH;

  const int t = threadIdx.x, wv = t >> 6, lane = t & 63;
  const int g = lane >> 4, c = lane & 15;
  const int q0 = qt * 64 + wv * 16;

  __shared__ __align__(16) unsigned short Pl[4][16][80];  // per-wave P exchange

  const unsigned short* qp = Qb + (size_t)(b * S_LEN + q0 + c) * DM + h * DH + 8 * g;
  const bf16x8 aq0 = *(const bf16x8*)qp;
  const bf16x8 aq1 = *(const bf16x8*)(qp + 32);

  const unsigned short* kbase = Kb + (size_t)b * S_LEN * DM + h * DH + 8 * g;
  const float* mrow = mask + (size_t)b * S_LEN;

  const unsigned short* vrow[4];
  #pragma unroll
  for (int dt = 0; dt < 4; ++dt)
    vrow[dt] = Vt + (size_t)((h * DH + dt * 16 + c) * BATCH + b) * S_LEN;

  float m = -1e30f, l = 0.f;

  // ---- pass 1: row max + sum (k-index = 4g+reg, q = c) ----
  for (int kt = 0; kt < S_LEN / 64; ++kt) {
    f32x4 s[4];
    #pragma unroll
    for (int sub = 0; sub < 4; ++sub) {
      s[sub] = *(const f32x4*)&mrow[kt * 64 + sub * 16 + 4 * g];  // mask as C-init
      const unsigned short* kp = kbase + (size_t)(kt * 64 + sub * 16 + c) * DM;
      bf16x8 bk0 = *(const bf16x8*)kp;
      bf16x8 bk1 = *(const bf16x8*)(kp + 32);
      s[sub] = __builtin_amdgcn_mfma_f32_16x16x32_bf16(bk0, aq0, s[sub], 0, 0, 0);
      s[sub] = __builtin_amdgcn_mfma_f32_16x16x32_bf16(bk1, aq1, s[sub], 0, 0, 0);
    }
    float tm = fmaxf(fmaxf(fmaxf(s[0][0], s[0][1]), fmaxf(s[0][2], s[0][3])),
                     fmaxf(fmaxf(s[1][0], s[1][1]), fmaxf(s[1][2], s[1][3])));
    tm = fmaxf(tm, fmaxf(fmaxf(fmaxf(s[2][0], s[2][1]), fmaxf(s[2][2], s[2][3])),
                         fmaxf(fmaxf(s[3][0], s[3][1]), fmaxf(s[3][2], s[3][3]))));
    tm = fmaxf(tm, __shfl_xor(tm, 16));
    tm = fmaxf(tm, __shfl_xor(tm, 32));
    const float mn = fmaxf(m, tm);
    float es = 0.f;
    #pragma unroll
    for (int sub = 0; sub < 4; ++sub)
      #pragma unroll
      for (int j = 0; j < 4; ++j) es += __expf(s[sub][j] - mn);
    es += __shfl_xor(es, 16);
    es += __shfl_xor(es, 32);
    l = l * __expf(m - mn) + es;
    m = mn;
  }
  const float invl = 1.f / l;

  f32x4 o[4];
  #pragma unroll
  for (int dt = 0; dt < 4; ++dt) { f32x4 zz = {0.f, 0.f, 0.f, 0.f}; o[dt] = zz; }

  float* prow = Pout + (size_t)(b * NH + h) * S_LEN * S_LEN + (size_t)(q0 + c) * S_LEN;

  // ---- pass 2: recompute scores, write P (dwordx4, nontemporal), PV ----
  for (int kt = 0; kt < S_LEN / 64; ++kt) {
    f32x4 s[4];
    #pragma unroll
    for (int sub = 0; sub < 4; ++sub) {
      s[sub] = *(const f32x4*)&mrow[kt * 64 + sub * 16 + 4 * g];
      const unsigned short* kp = kbase + (size_t)(kt * 64 + sub * 16 + c) * DM;
      bf16x8 bk0 = *(const bf16x8*)kp;
      bf16x8 bk1 = *(const bf16x8*)(kp + 32);
      s[sub] = __builtin_amdgcn_mfma_f32_16x16x32_bf16(bk0, aq0, s[sub], 0, 0, 0);
      s[sub] = __builtin_amdgcn_mfma_f32_16x16x32_bf16(bk1, aq1, s[sub], 0, 0, 0);
    }
    #pragma unroll
    for (int sub = 0; sub < 4; ++sub) {
      f32x4 p;
      #pragma unroll
      for (int j = 0; j < 4; ++j) p[j] = __expf(s[sub][j] - m) * invl;
      __builtin_nontemporal_store(p, (f32x4*)(prow + kt * 64 + sub * 16 + 4 * g));
      u16x4 pb;
      #pragma unroll
      for (int j = 0; j < 4; ++j) pb[j] = f2bf(p[j]);
      *(u16x4*)&Pl[wv][c][sub * 16 + 4 * g] = pb;  // row q=c, 4 consecutive k
    }
    #pragma unroll
    for (int ks = 0; ks < 2; ++ks) {
      const bf16x8 pa = *(const bf16x8*)&Pl[wv][c][ks * 32 + 8 * g];
      #pragma unroll
      for (int dt = 0; dt < 4; ++dt) {
        const bf16x8 vb = *(const bf16x8*)(vrow[dt] + kt * 64 + ks * 32 + 8 * g);
        o[dt] = __builtin_amdgcn_mfma_f32_16x16x32_bf16(pa, vb, o[dt], 0, 0, 0);
      }
    }
  }

  // O: row = q = 4g+j, col = d = dt*16 + c
  #pragma unroll
  for (int dt = 0; dt < 4; ++dt)
    #pragma unroll
    for (int j = 0; j < 4; ++j)
      ctx[(size_t)(b * S_LEN + q0 + 4 * g + j) * DM + h * DH + dt * 16 + c] = o[dt][j];
}

extern "C" void kernel_launch(void* const* d_in, const int* in_sizes, int n_in,
                              void* d_out, int out_size, void* d_ws, size_t ws_size,
                              hipStream_t stream) {
  const float* hs   = (const float*)d_in[0];
  const float* mask = (const float*)d_in[1];
  const float* Wq = (const float*)d_in[2];
  const float* bq = (const float*)d_in[3];
  const float* Wk = (const float*)d_in[4];
  const float* bk = (const float*)d_in[5];
  const float* Wv = (const float*)d_in[6];
  const float* bv = (const float*)d_in[7];

  const size_t MT = (size_t)BATCH * S_LEN * DM;
  unsigned short* Qb = (unsigned short*)d_ws;
  unsigned short* Kb = Qb + MT;
  unsigned short* Vt = Kb + MT;

  float* ctx  = (float*)d_out;
  float* Pout = ctx + MT;

  qkv_gemm<<<dim3(DM / BN, (BATCH * S_LEN) / BM, 3), 256, 0, stream>>>(
      hs, Wq, bq, Wk, bk, Wv, bv, Qb, Kb, Vt);
  attn_fused<<<dim3(32 * NH * BATCH), 256, 0, stream>>>(
      Qb, Kb, Vt, mask, ctx, Pout);
}